// Round 21
// baseline (280.113 us; speedup 1.0000x reference)
//
#include <hip/hip_runtime.h>
#include <hip/hip_bf16.h>

typedef __hip_bfloat16 bf16;
typedef __attribute__((ext_vector_type(8))) short short8;
typedef __attribute__((ext_vector_type(16))) float f32x16;

#define NS 256      // N_SEQ
#define NR 256      // N_RES
#define CM 256      // C_M
#define CZ 128      // C_Z
#define NH 8        // heads
#define CH 32       // head dim
#define LN_EPS 1e-5f
#define LOG2E 1.4426950408889634f
// (1/sqrt(32)) * log2(e): folded into w_q at pack time
#define SCALE2 (0.17677669529663687f * 1.4426950408889634f)

__device__ __forceinline__ unsigned pk_bf16(float lo, float hi) {
  unsigned r;
  asm volatile("v_cvt_pk_bf16_f32 %0, %1, %2" : "=v"(r) : "v"(lo), "v"(hi));
  return r;
}

__device__ __forceinline__ short8 load8(const bf16* p) {
  return __builtin_bit_cast(short8, *(const uint4*)p);
}

// ---------------------------------------------------------------------------
// Kernel P: merged prep = ln_m (blocks 0..16383) + bias (16384..32767) +
// pack_w (32768..32927). One launch fills the machine.
// ---------------------------------------------------------------------------
__global__ __launch_bounds__(256) void prep_kernel(
    const float* __restrict__ m, const float* __restrict__ lmw,
    const float* __restrict__ lmb, bf16* __restrict__ mn,
    const float* __restrict__ z, const float* __restrict__ lzw,
    const float* __restrict__ lzb, const float* __restrict__ wz,
    float* __restrict__ biasP,
    const float* __restrict__ wq, const float* __restrict__ wk,
    const float* __restrict__ wv, const float* __restrict__ wg,
    const float* __restrict__ wo, bf16* __restrict__ wp) {
  int bid = blockIdx.x;
  int lane = threadIdx.x & 63;

  if (bid < 16384) {
    // ---- ln_m: one wave per row (65536 rows), float4 loads, bf16x4 stores
    int row = bid * 4 + (threadIdx.x >> 6);

    float4 x = ((const float4*)(m + (size_t)row * CM))[lane];
    float sum = x.x + x.y + x.z + x.w;
    #pragma unroll
    for (int off = 32; off; off >>= 1) sum += __shfl_xor(sum, off);
    float mu = sum * (1.0f / CM);

    float dx = x.x - mu, dy = x.y - mu, dz = x.z - mu, dw = x.w - mu;
    float ss = dx * dx + dy * dy + dz * dz + dw * dw;
    #pragma unroll
    for (int off = 32; off; off >>= 1) ss += __shfl_xor(ss, off);
    float rs = rsqrtf(ss * (1.0f / CM) + LN_EPS);

    float4 wv4 = ((const float4*)lmw)[lane];
    float4 bv4 = ((const float4*)lmb)[lane];
    uint2 u;
    u.x = pk_bf16(dx * rs * wv4.x + bv4.x, dy * rs * wv4.y + bv4.y);
    u.y = pk_bf16(dz * rs * wv4.z + bv4.z, dw * rs * wv4.w + bv4.w);
    *(uint2*)(mn + (size_t)row * CM + lane * 4) = u;
  } else if (bid < 32768) {
    // ---- bias: one wave per z-row (65536 rows), shuffle-only, scatter
    int row = (bid - 16384) * 4 + (threadIdx.x >> 6);

    float2 x = ((const float2*)(z + (size_t)row * CZ))[lane];
    float sum = x.x + x.y;
    #pragma unroll
    for (int off = 32; off; off >>= 1) sum += __shfl_xor(sum, off);
    float mu = sum * (1.0f / CZ);

    float dx = x.x - mu, dy = x.y - mu;
    float ss = dx * dx + dy * dy;
    #pragma unroll
    for (int off = 32; off; off >>= 1) ss += __shfl_xor(ss, off);
    float rs = rsqrtf(ss * (1.0f / CZ) + LN_EPS);

    float2 wv2 = ((const float2*)lzw)[lane];
    float2 bv2 = ((const float2*)lzb)[lane];
    float zn0 = dx * rs * wv2.x + bv2.x;
    float zn1 = dy * rs * wv2.y + bv2.y;

    const float4* wzr = (const float4*)(wz + (size_t)lane * 2 * NH);
    float4 a0 = wzr[0], a1 = wzr[1];
    float4 a2 = wzr[2], a3 = wzr[3];

    float p0 = zn0 * a0.x + zn1 * a2.x;
    float p1 = zn0 * a0.y + zn1 * a2.y;
    float p2 = zn0 * a0.z + zn1 * a2.z;
    float p3 = zn0 * a0.w + zn1 * a2.w;
    float p4 = zn0 * a1.x + zn1 * a3.x;
    float p5 = zn0 * a1.y + zn1 * a3.y;
    float p6 = zn0 * a1.z + zn1 * a3.z;
    float p7 = zn0 * a1.w + zn1 * a3.w;
    #pragma unroll
    for (int off = 32; off; off >>= 1) {
      p0 += __shfl_xor(p0, off);
      p1 += __shfl_xor(p1, off);
      p2 += __shfl_xor(p2, off);
      p3 += __shfl_xor(p3, off);
      p4 += __shfl_xor(p4, off);
      p5 += __shfl_xor(p5, off);
      p6 += __shfl_xor(p6, off);
      p7 += __shfl_xor(p7, off);
    }

    if (lane < NH) {
      float s = lane == 0 ? p0 : lane == 1 ? p1 : lane == 2 ? p2
              : lane == 3 ? p3 : lane == 4 ? p4 : lane == 5 ? p5
              : lane == 6 ? p6 : p7;
      int i = row >> 8, j = row & 255;         // q = i, k = j
      int qt = i >> 5, lo2 = i & 31;
      int tt = j >> 5, rem = j & 31;
      int hi2 = (rem >> 2) & 1;
      int r = ((rem >> 3) << 2) | (rem & 3);
      int ifrag = tt * 16 + r;
      int lidx = hi2 * 32 + lo2;
      biasP[((((size_t)lane * 8 + qt) * 32 + (ifrag >> 2)) * 64 + lidx) * 4 +
            (ifrag & 3)] = s * LOG2E;
    }
  } else {
    // ---- pack_w: wp[mat][kc][hi][n][j] = w[kc*16+hi*8+j][n], wq prescaled
    int b2 = bid - 32768;           // 0..159
    int mat = b2 >> 5;
    const float* src = mat == 0 ? wq : mat == 1 ? wk : mat == 2 ? wv
                     : mat == 3 ? wg : wo;
    float sc = (mat == 0) ? SCALE2 : 1.0f;
    int t = (b2 & 31) * 256 + threadIdx.x;  // 0..8191
    int n = t & 255;
    int hi = (t >> 8) & 1;
    int kc = t >> 9;
    int kbase = kc * 16 + hi * 8;
    bf16 tmp[8];
    #pragma unroll
    for (int j = 0; j < 8; ++j)
      tmp[j] = __float2bfloat16(src[(size_t)(kbase + j) * 256 + n] * sc);
    *(uint4*)(wp + (size_t)mat * 65536 +
              ((size_t)(kc * 2 + hi) * 256 + n) * 8) = *(const uint4*)tmp;
  }
}

// ---------------------------------------------------------------------------
// Kernel 3: fused q/k/v/g projections via MFMA, two-half form, wave->matrix
// remap for B reuse (unchanged from the 286-us config).
// ---------------------------------------------------------------------------
__global__ __launch_bounds__(256, 3) void qkvg_mfma_kernel(
    const bf16* __restrict__ mn, const bf16* __restrict__ wp,
    const float* __restrict__ bg,
    bf16* __restrict__ qo, bf16* __restrict__ ko,
    bf16* __restrict__ vo, bf16* __restrict__ go) {
  int mat = blockIdx.x >> 9;           // 0..3: matrix (q,k,v,g)
  int mg = blockIdx.x & 511;           // m-group
  int wave = threadIdx.x >> 6;
  int lane = threadIdx.x & 63;
  int lo = lane & 31, hi = lane >> 5;
  size_t m0 = ((size_t)mg * 4 + wave) * 32;

  const bf16* arow = mn + (m0 + lo) * 256 + hi * 8;
  const bf16* wbase = wp + (size_t)mat * 65536 + ((size_t)hi * 256 + lo) * 8;
  bf16* outp = mat == 0 ? qo : mat == 1 ? ko : mat == 2 ? vo : go;

  #pragma unroll
  for (int half = 0; half < 2; ++half) {
    f32x16 acc[4] = {};
    #pragma unroll 4
    for (int kc = 0; kc < 16; ++kc) {
      short8 a = load8(arow + kc * 16);
      const bf16* wkc = wbase + (size_t)kc * 4096 + half * 4 * 256;
      #pragma unroll
      for (int ntl = 0; ntl < 4; ++ntl) {
        short8 b = load8(wkc + ntl * 256);
        acc[ntl] =
            __builtin_amdgcn_mfma_f32_32x32x16_bf16(a, b, acc[ntl], 0, 0, 0);
      }
    }
    if (mat == 3) {
      #pragma unroll
      for (int ntl = 0; ntl < 4; ++ntl) {
        int nt = half * 4 + ntl;
        float bgv = bg[nt * 32 + lo];
        #pragma unroll
        for (int r = 0; r < 16; ++r) {
          int crow = (r & 3) + ((r >> 2) << 3) + (hi << 2);
          float sv = 1.0f / (1.0f + __expf(-(acc[ntl][r] + bgv)));
          outp[(m0 + crow) * 256 + nt * 32 + lo] = __float2bfloat16(sv);
        }
      }
    } else {
      #pragma unroll
      for (int ntl = 0; ntl < 4; ++ntl) {
        int nt = half * 4 + ntl;
        #pragma unroll
        for (int r = 0; r < 16; ++r) {
          int crow = (r & 3) + ((r >> 2) << 3) + (hi << 2);
          outp[(m0 + crow) * 256 + nt * 32 + lo] =
              __float2bfloat16(acc[ntl][r]);
        }
      }
    }
  }
}

// ---------------------------------------------------------------------------
// Kernel 3b: vT[s][h][c][k] = vo[s][k][h*32+c]. One block per (s,h), LDS tile.
// ---------------------------------------------------------------------------
__global__ __launch_bounds__(256) void transpose_v_kernel(
    const bf16* __restrict__ vo, bf16* __restrict__ vT) {
  int s = blockIdx.x >> 3, h = blockIdx.x & 7;
  int t = threadIdx.x;
  __shared__ bf16 tile[256][40];  // stride 80 B (16B-aligned), conflict-light

  #pragma unroll
  for (int p = 0; p < 4; ++p) {
    int k = p * 64 + (t >> 2);
    int c0 = (t & 3) * 8;
    uint4 u = *(const uint4*)(vo + ((size_t)(s * 256 + k)) * 256 + h * 32 + c0);
    *(uint4*)&tile[k][c0] = u;
  }
  __syncthreads();

  int c = t >> 3, k0 = (t & 7) * 32;
  bf16 buf[32];
  #pragma unroll
  for (int j = 0; j < 32; ++j) buf[j] = tile[k0 + j][c];
  bf16* dst = vT + (((size_t)(s * 8 + h) * 32 + c) * 256 + k0);
  #pragma unroll
  for (int q = 0; q < 4; ++q)
    *(uint4*)(dst + q * 8) = *(const uint4*)(buf + q * 8);
}

// ---------------------------------------------------------------------------
// Kernel 4: MFMA attention, QUARTER-split: k in 4 chunks of 64 with only
// acc[2] live (32 AGPR + o 16 + ~68 VGPR ~= 116 regs -> 4 waves/SIMD,
// vs 3 at the previous two-half form). Phases stay burst-y (4 MFMA /
// 32 exp2 / 16 cvt_pk per quarter). float4 bias, no-max softmax, XCD swizzle.
// ---------------------------------------------------------------------------
__global__ __launch_bounds__(256, 4) void attn_mfma_kernel(
    const bf16* __restrict__ qb, const bf16* __restrict__ kb,
    const bf16* __restrict__ vT, const bf16* __restrict__ gb,
    const float* __restrict__ biasP, bf16* __restrict__ gob) {
  int wb = (blockIdx.x & 7) * 512 + (blockIdx.x >> 3);
  int wid = wb * 4 + (threadIdx.x >> 6);
  int lane = threadIdx.x & 63;
  int lo = lane & 31;
  int hi = lane >> 5;
  int s = wid >> 6;
  int h = (wid >> 3) & 7;
  int qt = wid & 7;
  int q0 = qt * 32;

  const size_t base = (size_t)s * NR * 256 + h * CH;

  const float4* bp4 =
      (const float4*)biasP + ((size_t)(h * 8 + qt) * 32) * 64 + lane;

  short8 qf[2];
  #pragma unroll
  for (int cc = 0; cc < 2; ++cc)
    qf[cc] = load8(qb + base + (size_t)(q0 + lo) * 256 + cc * 16 + hi * 8);

  const bf16* vt = vT + ((size_t)(s * NH + h) * CH + lo) * 256;

  f32x16 o = {};
  float l0 = 0.0f, l1 = 0.0f, l2 = 0.0f, l3 = 0.0f;

  #pragma unroll
  for (int qs = 0; qs < 4; ++qs) {
    // --- QK^T burst: acc[2] covers k in [qs*64, qs*64+64)
    f32x16 acc[2];
    __builtin_amdgcn_s_setprio(1);
    #pragma unroll
    for (int th = 0; th < 2; ++th) {
      int t = qs * 2 + th;
      short8 kf0 = load8(kb + base + (size_t)(t * 32 + lo) * 256 + hi * 8);
      short8 kf1 = load8(kb + base + (size_t)(t * 32 + lo) * 256 + 16 + hi * 8);
      f32x16 z = {};
      acc[th] = __builtin_amdgcn_mfma_f32_32x32x16_bf16(kf0, qf[0], z, 0, 0, 0);
      acc[th] =
          __builtin_amdgcn_mfma_f32_32x32x16_bf16(kf1, qf[1], acc[th], 0, 0, 0);
    }
    __builtin_amdgcn_s_setprio(0);

    // --- P = exp2(logit + bias), 4 parallel sum accumulators
    #pragma unroll
    for (int th = 0; th < 2; ++th) {
      int t = qs * 2 + th;
      #pragma unroll
      for (int j = 0; j < 4; ++j) {
        float4 b4 = bp4[(t * 4 + j) * 64];
        float e0 = exp2f(acc[th][j * 4 + 0] + b4.x);
        float e1 = exp2f(acc[th][j * 4 + 1] + b4.y);
        float e2 = exp2f(acc[th][j * 4 + 2] + b4.z);
        float e3 = exp2f(acc[th][j * 4 + 3] + b4.w);
        acc[th][j * 4 + 0] = e0;
        acc[th][j * 4 + 1] = e1;
        acc[th][j * 4 + 2] = e2;
        acc[th][j * 4 + 3] = e3;
        l0 += e0;
        l1 += e1;
        l2 += e2;
        l3 += e3;
      }
    }

    // --- pack P fragments + PV for this quarter's 4 16-k chunks
    #pragma unroll
    for (int kc2 = 0; kc2 < 4; ++kc2) {
      int th = kc2 >> 1;
      int rb = (kc2 & 1) << 3;
      unsigned uL0 = pk_bf16(acc[th][rb + 0], acc[th][rb + 1]);
      unsigned uL1 = pk_bf16(acc[th][rb + 2], acc[th][rb + 3]);
      unsigned uH0 = pk_bf16(acc[th][rb + 4], acc[th][rb + 5]);
      unsigned uH1 = pk_bf16(acc[th][rb + 6], acc[th][rb + 7]);
      unsigned sL0 = __shfl_xor(uL0, 32), sL1 = __shfl_xor(uL1, 32);
      unsigned sH0 = __shfl_xor(uH0, 32), sH1 = __shfl_xor(uH1, 32);
      uint4 pu;
      pu.x = hi ? sH0 : uL0;
      pu.y = hi ? sH1 : uL1;
      pu.z = hi ? uH0 : sL0;
      pu.w = hi ? uH1 : sL1;
      short8 pf = __builtin_bit_cast(short8, pu);
      short8 vf = load8(vt + (qs * 4 + kc2) * 16 + hi * 8);
      o = __builtin_amdgcn_mfma_f32_32x32x16_bf16(pf, vf, o, 0, 0, 0);
    }
  }

  float l = (l0 + l1) + (l2 + l3);
  l += __shfl_xor(l, 32);
  float linv = 1.0f / l;

  #pragma unroll
  for (int r = 0; r < 16; ++r) {
    int crow = (r & 3) + ((r >> 2) << 3) + (hi << 2);
    float li = __shfl(linv, crow);
    size_t idx = base + (size_t)(q0 + crow) * 256 + lo;
    float gg = __bfloat162float(gb[idx]);
    gob[idx] = __float2bfloat16(gg * o[r] * li);
  }
}

// ---------------------------------------------------------------------------
// Kernel 5: out = (g*o) @ w_o + b_o via MFMA. Wave = 32 rows x 128 cols
// (acc[4]); 4096 waves -> 4 waves/SIMD grid-potential.
// ---------------------------------------------------------------------------
__global__ __launch_bounds__(256, 4) void out_mfma_kernel(
    const bf16* __restrict__ gob, const bf16* __restrict__ wop,
    const float* __restrict__ bo, float* __restrict__ out) {
  int wid = blockIdx.x * 4 + (threadIdx.x >> 6);  // 0..4095
  int mt = wid >> 1;
  int half = wid & 1;
  int lane = threadIdx.x & 63;
  int lo = lane & 31, hi = lane >> 5;
  size_t m0 = (size_t)mt * 32;

  const bf16* arow = gob + (m0 + lo) * 256 + hi * 8;
  const bf16* wbase = wop + ((size_t)hi * 256 + lo) * 8;

  f32x16 acc[4] = {};
  #pragma unroll 4
  for (int kc = 0; kc < 16; ++kc) {
    short8 a = load8(arow + kc * 16);
    const bf16* wkc = wbase + (size_t)kc * 4096 + half * 4 * 256;
    #pragma unroll
    for (int ntl = 0; ntl < 4; ++ntl) {
      short8 b = load8(wkc + ntl * 256);
      acc[ntl] =
          __builtin_amdgcn_mfma_f32_32x32x16_bf16(a, b, acc[ntl], 0, 0, 0);
    }
  }

  #pragma unroll
  for (int ntl = 0; ntl < 4; ++ntl) {
    int nt = half * 4 + ntl;
    float bv = bo[nt * 32 + lo];
    #pragma unroll
    for (int r = 0; r < 16; ++r) {
      int crow = (r & 3) + ((r >> 2) << 3) + (hi << 2);
      out[(m0 + crow) * 256 + nt * 32 + lo] = acc[ntl][r] + bv;
    }
  }
}

// ---------------------------------------------------------------------------
extern "C" void kernel_launch(void* const* d_in, const int* in_sizes, int n_in,
                              void* d_out, int out_size, void* d_ws, size_t ws_size,
                              hipStream_t stream) {
  const float* m      = (const float*)d_in[0];
  const float* z      = (const float*)d_in[1];
  const float* ln_m_w = (const float*)d_in[2];
  const float* ln_m_b = (const float*)d_in[3];
  const float* ln_z_w = (const float*)d_in[4];
  const float* ln_z_b = (const float*)d_in[5];
  const float* w_z    = (const float*)d_in[6];
  const float* w_q    = (const float*)d_in[7];
  const float* w_k    = (const float*)d_in[8];
  const float* w_v    = (const float*)d_in[9];
  const float* w_g    = (const float*)d_in[10];
  const float* b_g    = (const float*)d_in[11];
  const float* w_o    = (const float*)d_in[12];
  const float* b_o    = (const float*)d_in[13];
  float* out = (float*)d_out;

  const size_t SZ = (size_t)NS * NR * 256;

  bf16* mn   = (bf16*)d_ws;
  bf16* qb   = mn + SZ;
  bf16* kb   = qb + SZ;
  bf16* vo   = kb + SZ;
  bf16* gb   = vo + SZ;
  bf16* gob  = gb + SZ;
  float* biasP = (float*)(gob + SZ);            // 2 MB
  bf16* wp   = (bf16*)(biasP + NH * NR * NR);   // 5*65536 bf16 = 640 KB
  bf16* wop  = wp + 4 * 65536;
  bf16* vT   = mn;  // mn is dead after qkvg; reuse its slot for vT

  prep_kernel<<<32928, 256, 0, stream>>>(m, ln_m_w, ln_m_b, mn,
                                         z, ln_z_w, ln_z_b, w_z, biasP,
                                         w_q, w_k, w_v, w_g, w_o, wp);
  qkvg_mfma_kernel<<<(NS * NR) / 32, 256, 0, stream>>>(mn, wp, b_g,
                                                       qb, kb, vo, gb);
  transpose_v_kernel<<<NS * NH, 256, 0, stream>>>(vo, vT);
  attn_mfma_kernel<<<(NS * NH * 8) / 4, 256, 0, stream>>>(qb, kb, vT, gb,
                                                          biasP, gob);
  out_mfma_kernel<<<(NS * NR) / 32 / 2, 256, 0, stream>>>(gob, wop, b_o, out);
}

// Round 22
// 279.271 us; speedup vs baseline: 1.0030x; 1.0030x over previous
//
#include <hip/hip_runtime.h>
#include <hip/hip_bf16.h>

typedef __hip_bfloat16 bf16;
typedef __attribute__((ext_vector_type(8))) short short8;
typedef __attribute__((ext_vector_type(16))) float f32x16;

#define NS 256      // N_SEQ
#define NR 256      // N_RES
#define CM 256      // C_M
#define CZ 128      // C_Z
#define NH 8        // heads
#define CH 32       // head dim
#define LN_EPS 1e-5f
#define LOG2E 1.4426950408889634f
// (1/sqrt(32)) * log2(e): folded into w_q at pack time
#define SCALE2 (0.17677669529663687f * 1.4426950408889634f)

__device__ __forceinline__ unsigned pk_bf16(float lo, float hi) {
  unsigned r;
  asm volatile("v_cvt_pk_bf16_f32 %0, %1, %2" : "=v"(r) : "v"(lo), "v"(hi));
  return r;
}

__device__ __forceinline__ short8 load8(const bf16* p) {
  return __builtin_bit_cast(short8, *(const uint4*)p);
}

// ---------------------------------------------------------------------------
// Kernel P: merged prep = ln_m (blocks 0..16383) + bias (16384..32767) +
// pack_w (32768..32927). One launch fills the machine.
// ---------------------------------------------------------------------------
__global__ __launch_bounds__(256) void prep_kernel(
    const float* __restrict__ m, const float* __restrict__ lmw,
    const float* __restrict__ lmb, bf16* __restrict__ mn,
    const float* __restrict__ z, const float* __restrict__ lzw,
    const float* __restrict__ lzb, const float* __restrict__ wz,
    float* __restrict__ biasP,
    const float* __restrict__ wq, const float* __restrict__ wk,
    const float* __restrict__ wv, const float* __restrict__ wg,
    const float* __restrict__ wo, bf16* __restrict__ wp) {
  int bid = blockIdx.x;
  int lane = threadIdx.x & 63;

  if (bid < 16384) {
    // ---- ln_m: one wave per row (65536 rows), float4 loads, bf16x4 stores
    int row = bid * 4 + (threadIdx.x >> 6);

    float4 x = ((const float4*)(m + (size_t)row * CM))[lane];
    float sum = x.x + x.y + x.z + x.w;
    #pragma unroll
    for (int off = 32; off; off >>= 1) sum += __shfl_xor(sum, off);
    float mu = sum * (1.0f / CM);

    float dx = x.x - mu, dy = x.y - mu, dz = x.z - mu, dw = x.w - mu;
    float ss = dx * dx + dy * dy + dz * dz + dw * dw;
    #pragma unroll
    for (int off = 32; off; off >>= 1) ss += __shfl_xor(ss, off);
    float rs = rsqrtf(ss * (1.0f / CM) + LN_EPS);

    float4 wv4 = ((const float4*)lmw)[lane];
    float4 bv4 = ((const float4*)lmb)[lane];
    uint2 u;
    u.x = pk_bf16(dx * rs * wv4.x + bv4.x, dy * rs * wv4.y + bv4.y);
    u.y = pk_bf16(dz * rs * wv4.z + bv4.z, dw * rs * wv4.w + bv4.w);
    *(uint2*)(mn + (size_t)row * CM + lane * 4) = u;
  } else if (bid < 32768) {
    // ---- bias: one wave per z-row (65536 rows), shuffle-only, scatter
    int row = (bid - 16384) * 4 + (threadIdx.x >> 6);

    float2 x = ((const float2*)(z + (size_t)row * CZ))[lane];
    float sum = x.x + x.y;
    #pragma unroll
    for (int off = 32; off; off >>= 1) sum += __shfl_xor(sum, off);
    float mu = sum * (1.0f / CZ);

    float dx = x.x - mu, dy = x.y - mu;
    float ss = dx * dx + dy * dy;
    #pragma unroll
    for (int off = 32; off; off >>= 1) ss += __shfl_xor(ss, off);
    float rs = rsqrtf(ss * (1.0f / CZ) + LN_EPS);

    float2 wv2 = ((const float2*)lzw)[lane];
    float2 bv2 = ((const float2*)lzb)[lane];
    float zn0 = dx * rs * wv2.x + bv2.x;
    float zn1 = dy * rs * wv2.y + bv2.y;

    const float4* wzr = (const float4*)(wz + (size_t)lane * 2 * NH);
    float4 a0 = wzr[0], a1 = wzr[1];
    float4 a2 = wzr[2], a3 = wzr[3];

    float p0 = zn0 * a0.x + zn1 * a2.x;
    float p1 = zn0 * a0.y + zn1 * a2.y;
    float p2 = zn0 * a0.z + zn1 * a2.z;
    float p3 = zn0 * a0.w + zn1 * a2.w;
    float p4 = zn0 * a1.x + zn1 * a3.x;
    float p5 = zn0 * a1.y + zn1 * a3.y;
    float p6 = zn0 * a1.z + zn1 * a3.z;
    float p7 = zn0 * a1.w + zn1 * a3.w;
    #pragma unroll
    for (int off = 32; off; off >>= 1) {
      p0 += __shfl_xor(p0, off);
      p1 += __shfl_xor(p1, off);
      p2 += __shfl_xor(p2, off);
      p3 += __shfl_xor(p3, off);
      p4 += __shfl_xor(p4, off);
      p5 += __shfl_xor(p5, off);
      p6 += __shfl_xor(p6, off);
      p7 += __shfl_xor(p7, off);
    }

    if (lane < NH) {
      float s = lane == 0 ? p0 : lane == 1 ? p1 : lane == 2 ? p2
              : lane == 3 ? p3 : lane == 4 ? p4 : lane == 5 ? p5
              : lane == 6 ? p6 : p7;
      int i = row >> 8, j = row & 255;         // q = i, k = j
      int qt = i >> 5, lo2 = i & 31;
      int tt = j >> 5, rem = j & 31;
      int hi2 = (rem >> 2) & 1;
      int r = ((rem >> 3) << 2) | (rem & 3);
      int ifrag = tt * 16 + r;
      int lidx = hi2 * 32 + lo2;
      biasP[((((size_t)lane * 8 + qt) * 32 + (ifrag >> 2)) * 64 + lidx) * 4 +
            (ifrag & 3)] = s * LOG2E;
    }
  } else {
    // ---- pack_w: wp[mat][kc][hi][n][j] = w[kc*16+hi*8+j][n], wq prescaled
    int b2 = bid - 32768;           // 0..159
    int mat = b2 >> 5;
    const float* src = mat == 0 ? wq : mat == 1 ? wk : mat == 2 ? wv
                     : mat == 3 ? wg : wo;
    float sc = (mat == 0) ? SCALE2 : 1.0f;
    int t = (b2 & 31) * 256 + threadIdx.x;  // 0..8191
    int n = t & 255;
    int hi = (t >> 8) & 1;
    int kc = t >> 9;
    int kbase = kc * 16 + hi * 8;
    bf16 tmp[8];
    #pragma unroll
    for (int j = 0; j < 8; ++j)
      tmp[j] = __float2bfloat16(src[(size_t)(kbase + j) * 256 + n] * sc);
    *(uint4*)(wp + (size_t)mat * 65536 +
              ((size_t)(kc * 2 + hi) * 256 + n) * 8) = *(const uint4*)tmp;
  }
}

// ---------------------------------------------------------------------------
// Kernel 3: fused q/k/v/g projections via MFMA, two-half form, wave->matrix
// remap for B reuse (unchanged from the 286-us config).
// ---------------------------------------------------------------------------
__global__ __launch_bounds__(256, 3) void qkvg_mfma_kernel(
    const bf16* __restrict__ mn, const bf16* __restrict__ wp,
    const float* __restrict__ bg,
    bf16* __restrict__ qo, bf16* __restrict__ ko,
    bf16* __restrict__ vo, bf16* __restrict__ go) {
  int mat = blockIdx.x >> 9;           // 0..3: matrix (q,k,v,g)
  int mg = blockIdx.x & 511;           // m-group
  int wave = threadIdx.x >> 6;
  int lane = threadIdx.x & 63;
  int lo = lane & 31, hi = lane >> 5;
  size_t m0 = ((size_t)mg * 4 + wave) * 32;

  const bf16* arow = mn + (m0 + lo) * 256 + hi * 8;
  const bf16* wbase = wp + (size_t)mat * 65536 + ((size_t)hi * 256 + lo) * 8;
  bf16* outp = mat == 0 ? qo : mat == 1 ? ko : mat == 2 ? vo : go;

  #pragma unroll
  for (int half = 0; half < 2; ++half) {
    f32x16 acc[4] = {};
    #pragma unroll 4
    for (int kc = 0; kc < 16; ++kc) {
      short8 a = load8(arow + kc * 16);
      const bf16* wkc = wbase + (size_t)kc * 4096 + half * 4 * 256;
      #pragma unroll
      for (int ntl = 0; ntl < 4; ++ntl) {
        short8 b = load8(wkc + ntl * 256);
        acc[ntl] =
            __builtin_amdgcn_mfma_f32_32x32x16_bf16(a, b, acc[ntl], 0, 0, 0);
      }
    }
    if (mat == 3) {
      #pragma unroll
      for (int ntl = 0; ntl < 4; ++ntl) {
        int nt = half * 4 + ntl;
        float bgv = bg[nt * 32 + lo];
        #pragma unroll
        for (int r = 0; r < 16; ++r) {
          int crow = (r & 3) + ((r >> 2) << 3) + (hi << 2);
          float sv = 1.0f / (1.0f + __expf(-(acc[ntl][r] + bgv)));
          outp[(m0 + crow) * 256 + nt * 32 + lo] = __float2bfloat16(sv);
        }
      }
    } else {
      #pragma unroll
      for (int ntl = 0; ntl < 4; ++ntl) {
        int nt = half * 4 + ntl;
        #pragma unroll
        for (int r = 0; r < 16; ++r) {
          int crow = (r & 3) + ((r >> 2) << 3) + (hi << 2);
          outp[(m0 + crow) * 256 + nt * 32 + lo] =
              __float2bfloat16(acc[ntl][r]);
        }
      }
    }
  }
}

// ---------------------------------------------------------------------------
// Kernel 3b: vT[s][h][c][k] = vo[s][k][h*32+c]. One block per (s,h), LDS tile.
// ---------------------------------------------------------------------------
__global__ __launch_bounds__(256) void transpose_v_kernel(
    const bf16* __restrict__ vo, bf16* __restrict__ vT) {
  int s = blockIdx.x >> 3, h = blockIdx.x & 7;
  int t = threadIdx.x;
  __shared__ bf16 tile[256][40];  // stride 80 B (16B-aligned), conflict-light

  #pragma unroll
  for (int p = 0; p < 4; ++p) {
    int k = p * 64 + (t >> 2);
    int c0 = (t & 3) * 8;
    uint4 u = *(const uint4*)(vo + ((size_t)(s * 256 + k)) * 256 + h * 32 + c0);
    *(uint4*)&tile[k][c0] = u;
  }
  __syncthreads();

  int c = t >> 3, k0 = (t & 7) * 32;
  bf16 buf[32];
  #pragma unroll
  for (int j = 0; j < 32; ++j) buf[j] = tile[k0 + j][c];
  bf16* dst = vT + (((size_t)(s * 8 + h) * 32 + c) * 256 + k0);
  #pragma unroll
  for (int q = 0; q < 4; ++q)
    *(uint4*)(dst + q * 8) = *(const uint4*)(buf + q * 8);
}

// ---------------------------------------------------------------------------
// Kernel 4: MFMA attention, QUARTER-split: k in 4 chunks of 64 with only
// acc[2] live (32 AGPR + o 16 + ~68 VGPR ~= 116 regs -> 4 waves/SIMD,
// vs 3 at the previous two-half form). Phases stay burst-y (4 MFMA /
// 32 exp2 / 16 cvt_pk per quarter). float4 bias, no-max softmax, XCD swizzle.
// ---------------------------------------------------------------------------
__global__ __launch_bounds__(256, 4) void attn_mfma_kernel(
    const bf16* __restrict__ qb, const bf16* __restrict__ kb,
    const bf16* __restrict__ vT, const bf16* __restrict__ gb,
    const float* __restrict__ biasP, bf16* __restrict__ gob) {
  int wb = (blockIdx.x & 7) * 512 + (blockIdx.x >> 3);
  int wid = wb * 4 + (threadIdx.x >> 6);
  int lane = threadIdx.x & 63;
  int lo = lane & 31;
  int hi = lane >> 5;
  int s = wid >> 6;
  int h = (wid >> 3) & 7;
  int qt = wid & 7;
  int q0 = qt * 32;

  const size_t base = (size_t)s * NR * 256 + h * CH;

  const float4* bp4 =
      (const float4*)biasP + ((size_t)(h * 8 + qt) * 32) * 64 + lane;

  short8 qf[2];
  #pragma unroll
  for (int cc = 0; cc < 2; ++cc)
    qf[cc] = load8(qb + base + (size_t)(q0 + lo) * 256 + cc * 16 + hi * 8);

  const bf16* vt = vT + ((size_t)(s * NH + h) * CH + lo) * 256;

  f32x16 o = {};
  float l0 = 0.0f, l1 = 0.0f, l2 = 0.0f, l3 = 0.0f;

  #pragma unroll
  for (int qs = 0; qs < 4; ++qs) {
    // --- QK^T burst: acc[2] covers k in [qs*64, qs*64+64)
    f32x16 acc[2];
    __builtin_amdgcn_s_setprio(1);
    #pragma unroll
    for (int th = 0; th < 2; ++th) {
      int t = qs * 2 + th;
      short8 kf0 = load8(kb + base + (size_t)(t * 32 + lo) * 256 + hi * 8);
      short8 kf1 = load8(kb + base + (size_t)(t * 32 + lo) * 256 + 16 + hi * 8);
      f32x16 z = {};
      acc[th] = __builtin_amdgcn_mfma_f32_32x32x16_bf16(kf0, qf[0], z, 0, 0, 0);
      acc[th] =
          __builtin_amdgcn_mfma_f32_32x32x16_bf16(kf1, qf[1], acc[th], 0, 0, 0);
    }
    __builtin_amdgcn_s_setprio(0);

    // --- P = exp2(logit + bias), 4 parallel sum accumulators
    #pragma unroll
    for (int th = 0; th < 2; ++th) {
      int t = qs * 2 + th;
      #pragma unroll
      for (int j = 0; j < 4; ++j) {
        float4 b4 = bp4[(t * 4 + j) * 64];
        float e0 = exp2f(acc[th][j * 4 + 0] + b4.x);
        float e1 = exp2f(acc[th][j * 4 + 1] + b4.y);
        float e2 = exp2f(acc[th][j * 4 + 2] + b4.z);
        float e3 = exp2f(acc[th][j * 4 + 3] + b4.w);
        acc[th][j * 4 + 0] = e0;
        acc[th][j * 4 + 1] = e1;
        acc[th][j * 4 + 2] = e2;
        acc[th][j * 4 + 3] = e3;
        l0 += e0;
        l1 += e1;
        l2 += e2;
        l3 += e3;
      }
    }

    // --- pack P fragments + PV for this quarter's 4 16-k chunks
    #pragma unroll
    for (int kc2 = 0; kc2 < 4; ++kc2) {
      int th = kc2 >> 1;
      int rb = (kc2 & 1) << 3;
      unsigned uL0 = pk_bf16(acc[th][rb + 0], acc[th][rb + 1]);
      unsigned uL1 = pk_bf16(acc[th][rb + 2], acc[th][rb + 3]);
      unsigned uH0 = pk_bf16(acc[th][rb + 4], acc[th][rb + 5]);
      unsigned uH1 = pk_bf16(acc[th][rb + 6], acc[th][rb + 7]);
      unsigned sL0 = __shfl_xor(uL0, 32), sL1 = __shfl_xor(uL1, 32);
      unsigned sH0 = __shfl_xor(uH0, 32), sH1 = __shfl_xor(uH1, 32);
      uint4 pu;
      pu.x = hi ? sH0 : uL0;
      pu.y = hi ? sH1 : uL1;
      pu.z = hi ? uH0 : sL0;
      pu.w = hi ? uH1 : sL1;
      short8 pf = __builtin_bit_cast(short8, pu);
      short8 vf = load8(vt + (qs * 4 + kc2) * 16 + hi * 8);
      o = __builtin_amdgcn_mfma_f32_32x32x16_bf16(pf, vf, o, 0, 0, 0);
    }
  }

  float l = (l0 + l1) + (l2 + l3);
  l += __shfl_xor(l, 32);
  float linv = 1.0f / l;

  #pragma unroll
  for (int r = 0; r < 16; ++r) {
    int crow = (r & 3) + ((r >> 2) << 3) + (hi << 2);
    float li = __shfl(linv, crow);
    size_t idx = base + (size_t)(q0 + crow) * 256 + lo;
    float gg = __bfloat162float(gb[idx]);
    gob[idx] = __float2bfloat16(gg * o[r] * li);
  }
}

// ---------------------------------------------------------------------------
// Kernel 5: out = (g*o) @ w_o + b_o via MFMA. Wave = 32 rows x 128 cols
// (acc[4]); 4096 waves -> 4 waves/SIMD grid-potential.
// ---------------------------------------------------------------------------
__global__ __launch_bounds__(256, 4) void out_mfma_kernel(
    const bf16* __restrict__ gob, const bf16* __restrict__ wop,
    const float* __restrict__ bo, float* __restrict__ out) {
  int wid = blockIdx.x * 4 + (threadIdx.x >> 6);  // 0..4095
  int mt = wid >> 1;
  int half = wid & 1;
  int lane = threadIdx.x & 63;
  int lo = lane & 31, hi = lane >> 5;
  size_t m0 = (size_t)mt * 32;

  const bf16* arow = gob + (m0 + lo) * 256 + hi * 8;
  const bf16* wbase = wop + ((size_t)hi * 256 + lo) * 8;

  f32x16 acc[4] = {};
  #pragma unroll 4
  for (int kc = 0; kc < 16; ++kc) {
    short8 a = load8(arow + kc * 16);
    const bf16* wkc = wbase + (size_t)kc * 4096 + half * 4 * 256;
    #pragma unroll
    for (int ntl = 0; ntl < 4; ++ntl) {
      short8 b = load8(wkc + ntl * 256);
      acc[ntl] =
          __builtin_amdgcn_mfma_f32_32x32x16_bf16(a, b, acc[ntl], 0, 0, 0);
    }
  }

  #pragma unroll
  for (int ntl = 0; ntl < 4; ++ntl) {
    int nt = half * 4 + ntl;
    float bv = bo[nt * 32 + lo];
    #pragma unroll
    for (int r = 0; r < 16; ++r) {
      int crow = (r & 3) + ((r >> 2) << 3) + (hi << 2);
      out[(m0 + crow) * 256 + nt * 32 + lo] = acc[ntl][r] + bv;
    }
  }
}

// ---------------------------------------------------------------------------
extern "C" void kernel_launch(void* const* d_in, const int* in_sizes, int n_in,
                              void* d_out, int out_size, void* d_ws, size_t ws_size,
                              hipStream_t stream) {
  const float* m      = (const float*)d_in[0];
  const float* z      = (const float*)d_in[1];
  const float* ln_m_w = (const float*)d_in[2];
  const float* ln_m_b = (const float*)d_in[3];
  const float* ln_z_w = (const float*)d_in[4];
  const float* ln_z_b = (const float*)d_in[5];
  const float* w_z    = (const float*)d_in[6];
  const float* w_q    = (const float*)d_in[7];
  const float* w_k    = (const float*)d_in[8];
  const float* w_v    = (const float*)d_in[9];
  const float* w_g    = (const float*)d_in[10];
  const float* b_g    = (const float*)d_in[11];
  const float* w_o    = (const float*)d_in[12];
  const float* b_o    = (const float*)d_in[13];
  float* out = (float*)d_out;

  const size_t SZ = (size_t)NS * NR * 256;

  bf16* mn   = (bf16*)d_ws;
  bf16* qb   = mn + SZ;
  bf16* kb   = qb + SZ;
  bf16* vo   = kb + SZ;
  bf16* gb   = vo + SZ;
  bf16* gob  = gb + SZ;
  float* biasP = (float*)(gob + SZ);            // 2 MB
  bf16* wp   = (bf16*)(biasP + NH * NR * NR);   // 5*65536 bf16 = 640 KB
  bf16* wop  = wp + 4 * 65536;
  bf16* vT   = mn;  // mn is dead after qkvg; reuse its slot for vT

  prep_kernel<<<32928, 256, 0, stream>>>(m, ln_m_w, ln_m_b, mn,
                                         z, ln_z_w, ln_z_b, w_z, biasP,
                                         w_q, w_k, w_v, w_g, w_o, wp);
  qkvg_mfma_kernel<<<(NS * NR) / 32, 256, 0, stream>>>(mn, wp, b_g,
                                                       qb, kb, vo, gb);
  transpose_v_kernel<<<NS * NH, 256, 0, stream>>>(vo, vT);
  attn_mfma_kernel<<<(NS * NH * 8) / 4, 256, 0, stream>>>(qb, kb, vT, gb,
                                                          biasP, gob);
  out_mfma_kernel<<<(NS * NR) / 32 / 2, 256, 0, stream>>>(gob, wop, b_o, out);
}

// Round 23
// 278.978 us; speedup vs baseline: 1.0041x; 1.0010x over previous
//
#include <hip/hip_runtime.h>
#include <hip/hip_bf16.h>

typedef __hip_bfloat16 bf16;
typedef __attribute__((ext_vector_type(8))) short short8;
typedef __attribute__((ext_vector_type(16))) float f32x16;

#define NS 256      // N_SEQ
#define NR 256      // N_RES
#define CM 256      // C_M
#define CZ 128      // C_Z
#define NH 8        // heads
#define CH 32       // head dim
#define LN_EPS 1e-5f
#define LOG2E 1.4426950408889634f
// (1/sqrt(32)) * log2(e): folded into w_q at pack time
#define SCALE2 (0.17677669529663687f * 1.4426950408889634f)

__device__ __forceinline__ unsigned pk_bf16(float lo, float hi) {
  unsigned r;
  asm volatile("v_cvt_pk_bf16_f32 %0, %1, %2" : "=v"(r) : "v"(lo), "v"(hi));
  return r;
}

__device__ __forceinline__ short8 load8(const bf16* p) {
  return __builtin_bit_cast(short8, *(const uint4*)p);
}

// ---------------------------------------------------------------------------
// Kernel P: merged prep = ln_m (blocks 0..16383) + bias (16384..32767) +
// pack_w (32768..32927). One launch fills the machine.
// ---------------------------------------------------------------------------
__global__ __launch_bounds__(256) void prep_kernel(
    const float* __restrict__ m, const float* __restrict__ lmw,
    const float* __restrict__ lmb, bf16* __restrict__ mn,
    const float* __restrict__ z, const float* __restrict__ lzw,
    const float* __restrict__ lzb, const float* __restrict__ wz,
    float* __restrict__ biasP,
    const float* __restrict__ wq, const float* __restrict__ wk,
    const float* __restrict__ wv, const float* __restrict__ wg,
    const float* __restrict__ wo, bf16* __restrict__ wp) {
  int bid = blockIdx.x;
  int lane = threadIdx.x & 63;

  if (bid < 16384) {
    // ---- ln_m: one wave per row (65536 rows), float4 loads, bf16x4 stores
    int row = bid * 4 + (threadIdx.x >> 6);

    float4 x = ((const float4*)(m + (size_t)row * CM))[lane];
    float sum = x.x + x.y + x.z + x.w;
    #pragma unroll
    for (int off = 32; off; off >>= 1) sum += __shfl_xor(sum, off);
    float mu = sum * (1.0f / CM);

    float dx = x.x - mu, dy = x.y - mu, dz = x.z - mu, dw = x.w - mu;
    float ss = dx * dx + dy * dy + dz * dz + dw * dw;
    #pragma unroll
    for (int off = 32; off; off >>= 1) ss += __shfl_xor(ss, off);
    float rs = rsqrtf(ss * (1.0f / CM) + LN_EPS);

    float4 wv4 = ((const float4*)lmw)[lane];
    float4 bv4 = ((const float4*)lmb)[lane];
    uint2 u;
    u.x = pk_bf16(dx * rs * wv4.x + bv4.x, dy * rs * wv4.y + bv4.y);
    u.y = pk_bf16(dz * rs * wv4.z + bv4.z, dw * rs * wv4.w + bv4.w);
    *(uint2*)(mn + (size_t)row * CM + lane * 4) = u;
  } else if (bid < 32768) {
    // ---- bias: one wave per z-row (65536 rows), shuffle-only, scatter
    int row = (bid - 16384) * 4 + (threadIdx.x >> 6);

    float2 x = ((const float2*)(z + (size_t)row * CZ))[lane];
    float sum = x.x + x.y;
    #pragma unroll
    for (int off = 32; off; off >>= 1) sum += __shfl_xor(sum, off);
    float mu = sum * (1.0f / CZ);

    float dx = x.x - mu, dy = x.y - mu;
    float ss = dx * dx + dy * dy;
    #pragma unroll
    for (int off = 32; off; off >>= 1) ss += __shfl_xor(ss, off);
    float rs = rsqrtf(ss * (1.0f / CZ) + LN_EPS);

    float2 wv2 = ((const float2*)lzw)[lane];
    float2 bv2 = ((const float2*)lzb)[lane];
    float zn0 = dx * rs * wv2.x + bv2.x;
    float zn1 = dy * rs * wv2.y + bv2.y;

    const float4* wzr = (const float4*)(wz + (size_t)lane * 2 * NH);
    float4 a0 = wzr[0], a1 = wzr[1];
    float4 a2 = wzr[2], a3 = wzr[3];

    float p0 = zn0 * a0.x + zn1 * a2.x;
    float p1 = zn0 * a0.y + zn1 * a2.y;
    float p2 = zn0 * a0.z + zn1 * a2.z;
    float p3 = zn0 * a0.w + zn1 * a2.w;
    float p4 = zn0 * a1.x + zn1 * a3.x;
    float p5 = zn0 * a1.y + zn1 * a3.y;
    float p6 = zn0 * a1.z + zn1 * a3.z;
    float p7 = zn0 * a1.w + zn1 * a3.w;
    #pragma unroll
    for (int off = 32; off; off >>= 1) {
      p0 += __shfl_xor(p0, off);
      p1 += __shfl_xor(p1, off);
      p2 += __shfl_xor(p2, off);
      p3 += __shfl_xor(p3, off);
      p4 += __shfl_xor(p4, off);
      p5 += __shfl_xor(p5, off);
      p6 += __shfl_xor(p6, off);
      p7 += __shfl_xor(p7, off);
    }

    if (lane < NH) {
      float s = lane == 0 ? p0 : lane == 1 ? p1 : lane == 2 ? p2
              : lane == 3 ? p3 : lane == 4 ? p4 : lane == 5 ? p5
              : lane == 6 ? p6 : p7;
      int i = row >> 8, j = row & 255;         // q = i, k = j
      int qt = i >> 5, lo2 = i & 31;
      int tt = j >> 5, rem = j & 31;
      int hi2 = (rem >> 2) & 1;
      int r = ((rem >> 3) << 2) | (rem & 3);
      int ifrag = tt * 16 + r;
      int lidx = hi2 * 32 + lo2;
      biasP[((((size_t)lane * 8 + qt) * 32 + (ifrag >> 2)) * 64 + lidx) * 4 +
            (ifrag & 3)] = s * LOG2E;
    }
  } else {
    // ---- pack_w: wp[mat][kc][hi][n][j] = w[kc*16+hi*8+j][n], wq prescaled
    int b2 = bid - 32768;           // 0..159
    int mat = b2 >> 5;
    const float* src = mat == 0 ? wq : mat == 1 ? wk : mat == 2 ? wv
                     : mat == 3 ? wg : wo;
    float sc = (mat == 0) ? SCALE2 : 1.0f;
    int t = (b2 & 31) * 256 + threadIdx.x;  // 0..8191
    int n = t & 255;
    int hi = (t >> 8) & 1;
    int kc = t >> 9;
    int kbase = kc * 16 + hi * 8;
    bf16 tmp[8];
    #pragma unroll
    for (int j = 0; j < 8; ++j)
      tmp[j] = __float2bfloat16(src[(size_t)(kbase + j) * 256 + n] * sc);
    *(uint4*)(wp + (size_t)mat * 65536 +
              ((size_t)(kc * 2 + hi) * 256 + n) * 8) = *(const uint4*)tmp;
  }
}

// ---------------------------------------------------------------------------
// Kernel 3: fused q/k/v/g projections via MFMA, two-half form, wave->matrix
// remap for B reuse (unchanged from the 286-us config).
// ---------------------------------------------------------------------------
__global__ __launch_bounds__(256, 3) void qkvg_mfma_kernel(
    const bf16* __restrict__ mn, const bf16* __restrict__ wp,
    const float* __restrict__ bg,
    bf16* __restrict__ qo, bf16* __restrict__ ko,
    bf16* __restrict__ vo, bf16* __restrict__ go) {
  int mat = blockIdx.x >> 9;           // 0..3: matrix (q,k,v,g)
  int mg = blockIdx.x & 511;           // m-group
  int wave = threadIdx.x >> 6;
  int lane = threadIdx.x & 63;
  int lo = lane & 31, hi = lane >> 5;
  size_t m0 = ((size_t)mg * 4 + wave) * 32;

  const bf16* arow = mn + (m0 + lo) * 256 + hi * 8;
  const bf16* wbase = wp + (size_t)mat * 65536 + ((size_t)hi * 256 + lo) * 8;
  bf16* outp = mat == 0 ? qo : mat == 1 ? ko : mat == 2 ? vo : go;

  #pragma unroll
  for (int half = 0; half < 2; ++half) {
    f32x16 acc[4] = {};
    #pragma unroll 4
    for (int kc = 0; kc < 16; ++kc) {
      short8 a = load8(arow + kc * 16);
      const bf16* wkc = wbase + (size_t)kc * 4096 + half * 4 * 256;
      #pragma unroll
      for (int ntl = 0; ntl < 4; ++ntl) {
        short8 b = load8(wkc + ntl * 256);
        acc[ntl] =
            __builtin_amdgcn_mfma_f32_32x32x16_bf16(a, b, acc[ntl], 0, 0, 0);
      }
    }
    if (mat == 3) {
      #pragma unroll
      for (int ntl = 0; ntl < 4; ++ntl) {
        int nt = half * 4 + ntl;
        float bgv = bg[nt * 32 + lo];
        #pragma unroll
        for (int r = 0; r < 16; ++r) {
          int crow = (r & 3) + ((r >> 2) << 3) + (hi << 2);
          float sv = 1.0f / (1.0f + __expf(-(acc[ntl][r] + bgv)));
          outp[(m0 + crow) * 256 + nt * 32 + lo] = __float2bfloat16(sv);
        }
      }
    } else {
      #pragma unroll
      for (int ntl = 0; ntl < 4; ++ntl) {
        int nt = half * 4 + ntl;
        #pragma unroll
        for (int r = 0; r < 16; ++r) {
          int crow = (r & 3) + ((r >> 2) << 3) + (hi << 2);
          outp[(m0 + crow) * 256 + nt * 32 + lo] =
              __float2bfloat16(acc[ntl][r]);
        }
      }
    }
  }
}

// ---------------------------------------------------------------------------
// Kernel 3b: vT[s][h][c][k] = vo[s][k][h*32+c]. One block per (s,h), LDS tile.
// ---------------------------------------------------------------------------
__global__ __launch_bounds__(256) void transpose_v_kernel(
    const bf16* __restrict__ vo, bf16* __restrict__ vT) {
  int s = blockIdx.x >> 3, h = blockIdx.x & 7;
  int t = threadIdx.x;
  __shared__ bf16 tile[256][40];  // stride 80 B (16B-aligned), conflict-light

  #pragma unroll
  for (int p = 0; p < 4; ++p) {
    int k = p * 64 + (t >> 2);
    int c0 = (t & 3) * 8;
    uint4 u = *(const uint4*)(vo + ((size_t)(s * 256 + k)) * 256 + h * 32 + c0);
    *(uint4*)&tile[k][c0] = u;
  }
  __syncthreads();

  int c = t >> 3, k0 = (t & 7) * 32;
  bf16 buf[32];
  #pragma unroll
  for (int j = 0; j < 32; ++j) buf[j] = tile[k0 + j][c];
  bf16* dst = vT + (((size_t)(s * 8 + h) * 32 + c) * 256 + k0);
  #pragma unroll
  for (int q = 0; q < 4; ++q)
    *(uint4*)(dst + q * 8) = *(const uint4*)(buf + q * 8);
}

// ---------------------------------------------------------------------------
// Kernel 4: MFMA attention, QUARTER-split: k in 4 chunks of 64 with only
// acc[2] live (32 AGPR + o 16 + ~68 VGPR ~= 116 regs -> 4 waves/SIMD,
// vs 3 at the previous two-half form). Phases stay burst-y (4 MFMA /
// 32 exp2 / 16 cvt_pk per quarter). float4 bias, no-max softmax, XCD swizzle.
// ---------------------------------------------------------------------------
__global__ __launch_bounds__(256, 4) void attn_mfma_kernel(
    const bf16* __restrict__ qb, const bf16* __restrict__ kb,
    const bf16* __restrict__ vT, const bf16* __restrict__ gb,
    const float* __restrict__ biasP, bf16* __restrict__ gob) {
  int wb = (blockIdx.x & 7) * 512 + (blockIdx.x >> 3);
  int wid = wb * 4 + (threadIdx.x >> 6);
  int lane = threadIdx.x & 63;
  int lo = lane & 31;
  int hi = lane >> 5;
  int s = wid >> 6;
  int h = (wid >> 3) & 7;
  int qt = wid & 7;
  int q0 = qt * 32;

  const size_t base = (size_t)s * NR * 256 + h * CH;

  const float4* bp4 =
      (const float4*)biasP + ((size_t)(h * 8 + qt) * 32) * 64 + lane;

  short8 qf[2];
  #pragma unroll
  for (int cc = 0; cc < 2; ++cc)
    qf[cc] = load8(qb + base + (size_t)(q0 + lo) * 256 + cc * 16 + hi * 8);

  const bf16* vt = vT + ((size_t)(s * NH + h) * CH + lo) * 256;

  f32x16 o = {};
  float l0 = 0.0f, l1 = 0.0f, l2 = 0.0f, l3 = 0.0f;

  #pragma unroll
  for (int qs = 0; qs < 4; ++qs) {
    // --- QK^T burst: acc[2] covers k in [qs*64, qs*64+64)
    f32x16 acc[2];
    __builtin_amdgcn_s_setprio(1);
    #pragma unroll
    for (int th = 0; th < 2; ++th) {
      int t = qs * 2 + th;
      short8 kf0 = load8(kb + base + (size_t)(t * 32 + lo) * 256 + hi * 8);
      short8 kf1 = load8(kb + base + (size_t)(t * 32 + lo) * 256 + 16 + hi * 8);
      f32x16 z = {};
      acc[th] = __builtin_amdgcn_mfma_f32_32x32x16_bf16(kf0, qf[0], z, 0, 0, 0);
      acc[th] =
          __builtin_amdgcn_mfma_f32_32x32x16_bf16(kf1, qf[1], acc[th], 0, 0, 0);
    }
    __builtin_amdgcn_s_setprio(0);

    // --- P = exp2(logit + bias), 4 parallel sum accumulators
    #pragma unroll
    for (int th = 0; th < 2; ++th) {
      int t = qs * 2 + th;
      #pragma unroll
      for (int j = 0; j < 4; ++j) {
        float4 b4 = bp4[(t * 4 + j) * 64];
        float e0 = exp2f(acc[th][j * 4 + 0] + b4.x);
        float e1 = exp2f(acc[th][j * 4 + 1] + b4.y);
        float e2 = exp2f(acc[th][j * 4 + 2] + b4.z);
        float e3 = exp2f(acc[th][j * 4 + 3] + b4.w);
        acc[th][j * 4 + 0] = e0;
        acc[th][j * 4 + 1] = e1;
        acc[th][j * 4 + 2] = e2;
        acc[th][j * 4 + 3] = e3;
        l0 += e0;
        l1 += e1;
        l2 += e2;
        l3 += e3;
      }
    }

    // --- pack P fragments + PV for this quarter's 4 16-k chunks
    #pragma unroll
    for (int kc2 = 0; kc2 < 4; ++kc2) {
      int th = kc2 >> 1;
      int rb = (kc2 & 1) << 3;
      unsigned uL0 = pk_bf16(acc[th][rb + 0], acc[th][rb + 1]);
      unsigned uL1 = pk_bf16(acc[th][rb + 2], acc[th][rb + 3]);
      unsigned uH0 = pk_bf16(acc[th][rb + 4], acc[th][rb + 5]);
      unsigned uH1 = pk_bf16(acc[th][rb + 6], acc[th][rb + 7]);
      unsigned sL0 = __shfl_xor(uL0, 32), sL1 = __shfl_xor(uL1, 32);
      unsigned sH0 = __shfl_xor(uH0, 32), sH1 = __shfl_xor(uH1, 32);
      uint4 pu;
      pu.x = hi ? sH0 : uL0;
      pu.y = hi ? sH1 : uL1;
      pu.z = hi ? uH0 : sL0;
      pu.w = hi ? uH1 : sL1;
      short8 pf = __builtin_bit_cast(short8, pu);
      short8 vf = load8(vt + (qs * 4 + kc2) * 16 + hi * 8);
      o = __builtin_amdgcn_mfma_f32_32x32x16_bf16(pf, vf, o, 0, 0, 0);
    }
  }

  float l = (l0 + l1) + (l2 + l3);
  l += __shfl_xor(l, 32);
  float linv = 1.0f / l;

  #pragma unroll
  for (int r = 0; r < 16; ++r) {
    int crow = (r & 3) + ((r >> 2) << 3) + (hi << 2);
    float li = __shfl(linv, crow);
    size_t idx = base + (size_t)(q0 + crow) * 256 + lo;
    float gg = __bfloat162float(gb[idx]);
    gob[idx] = __float2bfloat16(gg * o[r] * li);
  }
}

// ---------------------------------------------------------------------------
// Kernel 5: out = (g*o) @ w_o + b_o via MFMA. Wave = 32 rows x 128 cols
// (acc[4]); 4096 waves -> 4 waves/SIMD grid-potential.
// ---------------------------------------------------------------------------
__global__ __launch_bounds__(256, 4) void out_mfma_kernel(
    const bf16* __restrict__ gob, const bf16* __restrict__ wop,
    const float* __restrict__ bo, float* __restrict__ out) {
  int wid = blockIdx.x * 4 + (threadIdx.x >> 6);  // 0..4095
  int mt = wid >> 1;
  int half = wid & 1;
  int lane = threadIdx.x & 63;
  int lo = lane & 31, hi = lane >> 5;
  size_t m0 = (size_t)mt * 32;

  const bf16* arow = gob + (m0 + lo) * 256 + hi * 8;
  const bf16* wbase = wop + ((size_t)hi * 256 + lo) * 8;

  f32x16 acc[4] = {};
  #pragma unroll 4
  for (int kc = 0; kc < 16; ++kc) {
    short8 a = load8(arow + kc * 16);
    const bf16* wkc = wbase + (size_t)kc * 4096 + half * 4 * 256;
    #pragma unroll
    for (int ntl = 0; ntl < 4; ++ntl) {
      short8 b = load8(wkc + ntl * 256);
      acc[ntl] =
          __builtin_amdgcn_mfma_f32_32x32x16_bf16(a, b, acc[ntl], 0, 0, 0);
    }
  }

  #pragma unroll
  for (int ntl = 0; ntl < 4; ++ntl) {
    int nt = half * 4 + ntl;
    float bv = bo[nt * 32 + lo];
    #pragma unroll
    for (int r = 0; r < 16; ++r) {
      int crow = (r & 3) + ((r >> 2) << 3) + (hi << 2);
      out[(m0 + crow) * 256 + nt * 32 + lo] = acc[ntl][r] + bv;
    }
  }
}

// ---------------------------------------------------------------------------
extern "C" void kernel_launch(void* const* d_in, const int* in_sizes, int n_in,
                              void* d_out, int out_size, void* d_ws, size_t ws_size,
                              hipStream_t stream) {
  const float* m      = (const float*)d_in[0];
  const float* z      = (const float*)d_in[1];
  const float* ln_m_w = (const float*)d_in[2];
  const float* ln_m_b = (const float*)d_in[3];
  const float* ln_z_w = (const float*)d_in[4];
  const float* ln_z_b = (const float*)d_in[5];
  const float* w_z    = (const float*)d_in[6];
  const float* w_q    = (const float*)d_in[7];
  const float* w_k    = (const float*)d_in[8];
  const float* w_v    = (const float*)d_in[9];
  const float* w_g    = (const float*)d_in[10];
  const float* b_g    = (const float*)d_in[11];
  const float* w_o    = (const float*)d_in[12];
  const float* b_o    = (const float*)d_in[13];
  float* out = (float*)d_out;

  const size_t SZ = (size_t)NS * NR * 256;

  bf16* mn   = (bf16*)d_ws;
  bf16* qb   = mn + SZ;
  bf16* kb   = qb + SZ;
  bf16* vo   = kb + SZ;
  bf16* gb   = vo + SZ;
  bf16* gob  = gb + SZ;
  float* biasP = (float*)(gob + SZ);            // 2 MB
  bf16* wp   = (bf16*)(biasP + NH * NR * NR);   // 5*65536 bf16 = 640 KB
  bf16* wop  = wp + 4 * 65536;
  bf16* vT   = mn;  // mn is dead after qkvg; reuse its slot for vT

  prep_kernel<<<32928, 256, 0, stream>>>(m, ln_m_w, ln_m_b, mn,
                                         z, ln_z_w, ln_z_b, w_z, biasP,
                                         w_q, w_k, w_v, w_g, w_o, wp);
  qkvg_mfma_kernel<<<(NS * NR) / 32, 256, 0, stream>>>(mn, wp, b_g,
                                                       qb, kb, vo, gb);
  transpose_v_kernel<<<NS * NH, 256, 0, stream>>>(vo, vT);
  attn_mfma_kernel<<<(NS * NH * 8) / 4, 256, 0, stream>>>(qb, kb, vT, gb,
                                                          biasP, gob);
  out_mfma_kernel<<<(NS * NR) / 32 / 2, 256, 0, stream>>>(gob, wop, b_o, out);
}